// Round 1
// 1076.929 us; speedup vs baseline: 1.0175x; 1.0175x over previous
//
#include <hip/hip_runtime.h>
#include <stdint.h>

#define NTOK 65536
#define KDIM 1280

typedef __attribute__((ext_vector_type(8))) short short8;
typedef __attribute__((ext_vector_type(4))) float floatx4;

__device__ __forceinline__ unsigned short f2bf(float f) {
  union { float f; unsigned int u; } v; v.f = f;
  unsigned int r = v.u + 0x7FFFu + ((v.u >> 16) & 1u);  // RNE
  return (unsigned short)(r >> 16);
}

// async global->LDS, 16B per lane; lds base wave-uniform (HW adds lane*16)
#define GLDS16(gp, lp) \
  __builtin_amdgcn_global_load_lds((const __attribute__((address_space(1))) void*)(gp), \
                                   (__attribute__((address_space(3))) void*)(lp), 16, 0, 0)

// ---------------- prep kernels ----------------

__global__ __launch_bounds__(256) void cast_x_kernel(const float4* __restrict__ x,
                                                     uint2* __restrict__ xb) {
  size_t i = (size_t)blockIdx.x * 256 + threadIdx.x;
  float4 v = x[i];
  uint2 o;
  o.x = (unsigned)f2bf(v.x) | ((unsigned)f2bf(v.y) << 16);
  o.y = (unsigned)f2bf(v.z) | ((unsigned)f2bf(v.w) << 16);
  xb[i] = o;
}

// W1 [E][1280][256] f32 -> W1t [n=e*256+h][k] bf16
__global__ __launch_bounds__(256) void pack_w1_kernel(const float* __restrict__ W1,
                                                      unsigned short* __restrict__ W1t) {
  int t = blockIdx.x * 256 + threadIdx.x;
  if (t >= 2048 * 160) return;
  int n = t / 160, kg = t - n * 160;
  int e = n >> 8, h = n & 255;
  int k = kg * 8;
  const float* src = W1 + ((size_t)e * 1280 + k) * 256 + h;
  uint4 o;
  o.x = (unsigned)f2bf(src[0])       | ((unsigned)f2bf(src[256])     << 16);
  o.y = (unsigned)f2bf(src[2 * 256]) | ((unsigned)f2bf(src[3 * 256]) << 16);
  o.z = (unsigned)f2bf(src[4 * 256]) | ((unsigned)f2bf(src[5 * 256]) << 16);
  o.w = (unsigned)f2bf(src[6 * 256]) | ((unsigned)f2bf(src[7 * 256]) << 16);
  *(uint4*)(W1t + (size_t)n * 1280 + k) = o;
}

// W2 [E][256][128] f32 -> W2t [e][n=0..127][k=0..255] bf16
__global__ __launch_bounds__(256) void pack_w2_kernel(const float* __restrict__ W2,
                                                      unsigned short* __restrict__ W2t) {
  int t = blockIdx.x * 256 + threadIdx.x;
  if (t >= 1024 * 32) return;
  int ng = t >> 5, kg = t & 31;
  int e = ng >> 7, n = ng & 127;
  int k = kg * 8;
  const float* src = W2 + (size_t)e * 32768 + (size_t)k * 128 + n;
  uint4 o;
  o.x = (unsigned)f2bf(src[0])       | ((unsigned)f2bf(src[128])     << 16);
  o.y = (unsigned)f2bf(src[2 * 128]) | ((unsigned)f2bf(src[3 * 128]) << 16);
  o.z = (unsigned)f2bf(src[4 * 128]) | ((unsigned)f2bf(src[5 * 128]) << 16);
  o.w = (unsigned)f2bf(src[6 * 128]) | ((unsigned)f2bf(src[7 * 128]) << 16);
  *(uint4*)(W2t + (size_t)ng * 256 + k) = o;
}

// Wg [1280][8] f32 -> WgTb [16][1280] bf16 (rows 8..15 zero-pad)
__global__ __launch_bounds__(256) void pack_wg_kernel(const float* __restrict__ Wg,
                                                      unsigned short* __restrict__ WgTb) {
  int t = blockIdx.x * 256 + threadIdx.x;
  if (t >= 16 * 1280) return;
  int e = t / 1280, k = t - e * 1280;
  WgTb[t] = (e < 8) ? f2bf(Wg[(size_t)k * 8 + e]) : (unsigned short)0;
}

// ---------------- fused expert MLP (+gate on e==0 blocks) ----------------
// grid (8 experts, 1024 token-tiles of 64). 256 thr = 4 waves.
// LDS pool = exactly 53248 B -> 3 blocks/CU (was 57344 -> 2 blocks/CU).
//   Ws  [256][32] 16KB  (phase2 uses first 8KB)
//   Xs  [64][32]   4KB  (phase3 reuses as exS)
//   h1L [64][256] 32KB  XOR-swizzled (byte ^= (row&7)<<4), no pad
// Gate: e==0 blocks stage a [16][32] WgT sub-tile (into h1L area, dead in
// phase 1) and run 1 extra MFMA/wave/K-step; softmax epilogue writes outG.

__global__ __launch_bounds__(256)
void expert_fused_kernel(const unsigned short* __restrict__ xb,
                         const unsigned short* __restrict__ W1t,
                         const float* __restrict__ b1,
                         const unsigned short* __restrict__ W2t,
                         const float* __restrict__ b2,
                         const float* __restrict__ W3,
                         const float* __restrict__ b3,
                         const unsigned short* __restrict__ WgTb,
                         const float* __restrict__ bg,
                         float* __restrict__ outG,
                         float* __restrict__ eo) {
  __shared__ __align__(16) unsigned short smem[26624];  // 53248 bytes exactly
  unsigned short* Ws  = smem;           // 8192 shorts
  unsigned short* Xs  = smem + 8192;    // 2048 shorts
  unsigned short* h1L = smem + 10240;   // 16384 shorts
  unsigned short* WgS = h1L;            // [16][32] overlay, phase-1 only

  const int tid = threadIdx.x;
  const int wv = tid >> 6;
  const int lane = tid & 63;
  const int e = blockIdx.x;
  const int m0 = blockIdx.y << 6;
  const bool gate_blk = (e == 0);

  const unsigned short* W1te = W1t + (size_t)e * 256 * 1280;
  const unsigned short* W2te = W2t + (size_t)e * 128 * 256;

  const int lr = lane >> 2;                                    // staging row-in-16
  const int ksw = ((lane & 3) ^ ((lane >> 3) & 3)) * 8;        // swizzled src k-offset
  const int fr = lane & 15;
  const int fkS = (((lane >> 4) ^ ((lane >> 1) & 3)) & 3) * 8; // swizzled frag slot
  const int fkL = (lane >> 4) * 8;                             // logical frag k-offset
  const int rq = (lane >> 4) * 4;

  const unsigned short* gx = xb + (size_t)(m0 + wv * 16 + lr) * 1280 + ksw;
  const unsigned short* gw = W1te + (size_t)(wv * 64 + lr) * 1280 + ksw;
  const unsigned short* gwg = WgTb + (size_t)lr * 1280 + ksw;
  unsigned short* lx = &Xs[(wv * 16) * 32];
  unsigned short* lw = &Ws[(wv * 64) * 32];
  const bool gate_stager = gate_blk && (wv == 0);

  // ---- phase 1: h1^T tile (256 hidden x 64 tokens), K=1280 ----
  floatx4 acc1[4][4] = {};
  floatx4 accg = {0.f, 0.f, 0.f, 0.f};
  for (int k0 = 0; k0 < 1280; k0 += 32) {
    GLDS16(gx + k0, lx);
    GLDS16(gw + k0, lw);
    GLDS16(gw + (size_t)16 * 1280 + k0, lw + 16 * 32);
    GLDS16(gw + (size_t)32 * 1280 + k0, lw + 32 * 32);
    GLDS16(gw + (size_t)48 * 1280 + k0, lw + 48 * 32);
    if (gate_stager) GLDS16(gwg + k0, WgS);
    __syncthreads();
    short8 af[4], bfv[4];
#pragma unroll
    for (int i = 0; i < 4; i++)
      af[i] = *(const short8*)&Ws[(wv * 64 + i * 16 + fr) * 32 + fkS];
#pragma unroll
    for (int j = 0; j < 4; j++)
      bfv[j] = *(const short8*)&Xs[(j * 16 + fr) * 32 + fkS];
#pragma unroll
    for (int i = 0; i < 4; i++)
#pragma unroll
      for (int j = 0; j < 4; j++)
        acc1[i][j] = __builtin_amdgcn_mfma_f32_16x16x32_bf16(af[i], bfv[j], acc1[i][j], 0, 0, 0);
    if (gate_blk) {
      short8 ag = *(const short8*)&WgS[fr * 32 + fkS];
      short8 bgf = *(const short8*)&Xs[(wv * 16 + fr) * 32 + fkS];  // j = wv group
      accg = __builtin_amdgcn_mfma_f32_16x16x32_bf16(ag, bgf, accg, 0, 0, 0);
    }
    __syncthreads();
  }

  // ---- gate epilogue (e==0 blocks): softmax over 8 experts, write outG ----
  // accg layout: col(lane&15)=token-in-group(wv), row((lane>>4)*4+r)=expert.
  if (gate_blk) {
    const int g = lane >> 4;
    float bg0 = 0.f, bg1 = 0.f, bg2 = 0.f, bg3 = 0.f;
    if (g < 2) {
      float4 t = *(const float4*)(bg + g * 4);
      bg0 = t.x; bg1 = t.y; bg2 = t.z; bg3 = t.w;
    }
    float v0 = accg[0] + bg0, v1 = accg[1] + bg1, v2 = accg[2] + bg2, v3 = accg[3] + bg3;
    float mx = fmaxf(fmaxf(v0, v1), fmaxf(v2, v3));
    mx = fmaxf(mx, __shfl_xor(mx, 16));  // pairs g0<->g1 (g2/g3 junk stays separate)
    float e0 = __expf(v0 - mx), e1 = __expf(v1 - mx), e2 = __expf(v2 - mx), e3 = __expf(v3 - mx);
    float s = e0 + e1 + e2 + e3;
    s += __shfl_xor(s, 16);
    float inv = 1.f / s;
    if (g < 2) {
      float4 o; o.x = e0 * inv; o.y = e1 * inv; o.z = e2 * inv; o.w = e3 * inv;
      *(float4*)&outG[(size_t)(m0 + wv * 16 + fr) * 8 + g * 4] = o;
    }
  }

  // ---- epilogue 1: relu(+b1), bf16, transpose into swizzled h1L[token][k] ----
#pragma unroll
  for (int i = 0; i < 4; i++) {
    const int rowb = wv * 64 + i * 16 + rq;  // hidden k-index base (4 consecutive)
    const float4 bb = *(const float4*)(b1 + e * 256 + rowb);  // L2-hot
#pragma unroll
    for (int j = 0; j < 4; j++) {
      float v0 = acc1[i][j][0] + bb.x; v0 = v0 > 0.f ? v0 : 0.f;
      float v1 = acc1[i][j][1] + bb.y; v1 = v1 > 0.f ? v1 : 0.f;
      float v2 = acc1[i][j][2] + bb.z; v2 = v2 > 0.f ? v2 : 0.f;
      float v3 = acc1[i][j][3] + bb.w; v3 = v3 > 0.f ? v3 : 0.f;
      uint2 pk;
      pk.x = (unsigned)f2bf(v0) | ((unsigned)f2bf(v1) << 16);
      pk.y = (unsigned)f2bf(v2) | ((unsigned)f2bf(v3) << 16);
      const int row = j * 16 + fr;  // token row
      *(uint2*)((char*)h1L + ((row * 512 + rowb * 2) ^ ((row & 7) << 4))) = pk;
    }
  }
  __syncthreads();

  // ---- phase 2: h2 tile (128 h2 x 64 tokens), K=256 ----
  floatx4 acc2[2][4] = {};
  const unsigned short* gw2 = W2te + (size_t)(wv * 32 + lr) * 256 + ksw;
  unsigned short* lw2 = &Ws[(wv * 32) * 32];
  for (int k0 = 0; k0 < 256; k0 += 32) {
    GLDS16(gw2 + k0, lw2);
    GLDS16(gw2 + 16 * 256 + k0, lw2 + 16 * 32);
    __syncthreads();
    short8 a2[2], b2v[4];
#pragma unroll
    for (int i = 0; i < 2; i++)
      a2[i] = *(const short8*)&Ws[(wv * 32 + i * 16 + fr) * 32 + fkS];
#pragma unroll
    for (int j = 0; j < 4; j++) {
      const int row = j * 16 + fr;
      b2v[j] = *(const short8*)((const char*)h1L +
               ((row * 512 + (k0 + fkL) * 2) ^ ((row & 7) << 4)));
    }
#pragma unroll
    for (int i = 0; i < 2; i++)
#pragma unroll
      for (int j = 0; j < 4; j++)
        acc2[i][j] = __builtin_amdgcn_mfma_f32_16x16x32_bf16(a2[i], b2v[j], acc2[i][j], 0, 0, 0);
    __syncthreads();
  }

  // ---- phase 3: expert_out = relu(h2+b2) . W3 ----
  float psum[4] = {0.f, 0.f, 0.f, 0.f};
#pragma unroll
  for (int i = 0; i < 2; i++) {
    const int rowb = wv * 32 + i * 16 + rq;  // h2 index base
    const float4 bb = *(const float4*)(b2 + e * 128 + rowb);
    const float4 ww = *(const float4*)(W3 + e * 128 + rowb);
    const float bba[4] = {bb.x, bb.y, bb.z, bb.w};
    const float wwa[4] = {ww.x, ww.y, ww.z, ww.w};
#pragma unroll
    for (int j = 0; j < 4; j++)
#pragma unroll
      for (int r = 0; r < 4; r++) {
        float v = acc2[i][j][r] + bba[r];
        v = v > 0.f ? v : 0.f;
        psum[j] += v * wwa[r];
      }
  }
#pragma unroll
  for (int j = 0; j < 4; j++) {
    float v = psum[j];
    v += __shfl_xor(v, 16);
    v += __shfl_xor(v, 32);
    psum[j] = v;
  }
  float* exS = (float*)Xs;  // Xs dead since phase 1
  if (lane < 16) {
#pragma unroll
    for (int j = 0; j < 4; j++) exS[wv * 64 + j * 16 + lane] = psum[j];
  }
  __syncthreads();
  if (tid < 64) {
    float tot = exS[tid] + exS[64 + tid] + exS[128 + tid] + exS[192 + tid];
    eo[(size_t)(m0 + tid) * 8 + e] = tot + b3[e];
  }
}

// ---------------- combine: predictions = sum(gate * eo) ----------------

__global__ __launch_bounds__(256)
void combine_kernel(const float* __restrict__ outG, const float* __restrict__ eo,
                    float* __restrict__ outP) {
  int t = blockIdx.x * 256 + threadIdx.x;
  const float4* g4 = (const float4*)(outG + (size_t)t * 8);
  const float4* e4 = (const float4*)(eo + (size_t)t * 8);
  float4 ga = g4[0], gb = g4[1], ea = e4[0], eb = e4[1];
  outP[t] = ga.x * ea.x + ga.y * ea.y + ga.z * ea.z + ga.w * ea.w +
            gb.x * eb.x + gb.y * eb.y + gb.z * eb.z + gb.w * eb.w;
}

// ---------------- launch ----------------

extern "C" void kernel_launch(void* const* d_in, const int* in_sizes, int n_in,
                              void* d_out, int out_size, void* d_ws, size_t ws_size,
                              hipStream_t stream) {
  const float* x  = (const float*)d_in[0];
  const float* W1 = (const float*)d_in[1];
  const float* b1 = (const float*)d_in[2];
  const float* W2 = (const float*)d_in[3];
  const float* b2 = (const float*)d_in[4];
  const float* W3 = (const float*)d_in[5];
  const float* b3 = (const float*)d_in[6];
  const float* Wg = (const float*)d_in[7];
  const float* bg = (const float*)d_in[8];
  float* outP = (float*)d_out;   // predictions [B] f32
  float* outG = outP + NTOK;     // gate [B][8] f32

  char* ws = (char*)d_ws;
  unsigned short* xb   = (unsigned short*)ws;                 // 167,772,160
  unsigned short* W1t  = (unsigned short*)(ws + 167772160ll); //   5,242,880
  unsigned short* W2t  = (unsigned short*)(ws + 173015040ll); //     524,288
  unsigned short* WgTb = (unsigned short*)(ws + 173539328ll); //      40,960
  float*          eo   = (float*)(ws + 173580288ll);          //   2,097,152  (tot ~175.7MB)

  cast_x_kernel<<<NTOK * KDIM / 4 / 256, 256, 0, stream>>>((const float4*)x, (uint2*)xb);
  pack_w1_kernel<<<1280, 256, 0, stream>>>(W1, W1t);
  pack_w2_kernel<<<128, 256, 0, stream>>>(W2, W2t);
  pack_wg_kernel<<<80, 256, 0, stream>>>(Wg, WgTb);

  expert_fused_kernel<<<dim3(8, 1024), 256, 0, stream>>>(xb, W1t, b1, W2t, b2, W3, b3,
                                                         WgTb, bg, outG, eo);
  combine_kernel<<<256, 256, 0, stream>>>(outG, eo, outP);
}

// Round 2
// 1006.016 us; speedup vs baseline: 1.0893x; 1.0705x over previous
//
#include <hip/hip_runtime.h>
#include <stdint.h>

#define NTOK 65536
#define KDIM 1280

typedef __attribute__((ext_vector_type(8))) short short8;
typedef __attribute__((ext_vector_type(4))) float floatx4;

__device__ __forceinline__ unsigned short f2bf(float f) {
  union { float f; unsigned int u; } v; v.f = f;
  unsigned int r = v.u + 0x7FFFu + ((v.u >> 16) & 1u);  // RNE
  return (unsigned short)(r >> 16);
}

// async global->LDS, 16B per lane; lds base wave-uniform (HW adds lane*16)
#define GLDS16(gp, lp) \
  __builtin_amdgcn_global_load_lds((const __attribute__((address_space(1))) void*)(gp), \
                                   (__attribute__((address_space(3))) void*)(lp), 16, 0, 0)

// ---------------- prep kernels ----------------

__global__ __launch_bounds__(256) void cast_x_kernel(const float4* __restrict__ x,
                                                     uint2* __restrict__ xb) {
  size_t i = (size_t)blockIdx.x * 256 + threadIdx.x;
  float4 v = x[i];
  uint2 o;
  o.x = (unsigned)f2bf(v.x) | ((unsigned)f2bf(v.y) << 16);
  o.y = (unsigned)f2bf(v.z) | ((unsigned)f2bf(v.w) << 16);
  xb[i] = o;
}

// W1 [E][1280][256] f32 -> W1t [n=e*256+h][k] bf16
__global__ __launch_bounds__(256) void pack_w1_kernel(const float* __restrict__ W1,
                                                      unsigned short* __restrict__ W1t) {
  int t = blockIdx.x * 256 + threadIdx.x;
  if (t >= 2048 * 160) return;
  int n = t / 160, kg = t - n * 160;
  int e = n >> 8, h = n & 255;
  int k = kg * 8;
  const float* src = W1 + ((size_t)e * 1280 + k) * 256 + h;
  uint4 o;
  o.x = (unsigned)f2bf(src[0])       | ((unsigned)f2bf(src[256])     << 16);
  o.y = (unsigned)f2bf(src[2 * 256]) | ((unsigned)f2bf(src[3 * 256]) << 16);
  o.z = (unsigned)f2bf(src[4 * 256]) | ((unsigned)f2bf(src[5 * 256]) << 16);
  o.w = (unsigned)f2bf(src[6 * 256]) | ((unsigned)f2bf(src[7 * 256]) << 16);
  *(uint4*)(W1t + (size_t)n * 1280 + k) = o;
}

// W2 [E][256][128] f32 -> W2t [e][n=0..127][k=0..255] bf16
__global__ __launch_bounds__(256) void pack_w2_kernel(const float* __restrict__ W2,
                                                      unsigned short* __restrict__ W2t) {
  int t = blockIdx.x * 256 + threadIdx.x;
  if (t >= 1024 * 32) return;
  int ng = t >> 5, kg = t & 31;
  int e = ng >> 7, n = ng & 127;
  int k = kg * 8;
  const float* src = W2 + (size_t)e * 32768 + (size_t)k * 128 + n;
  uint4 o;
  o.x = (unsigned)f2bf(src[0])       | ((unsigned)f2bf(src[128])     << 16);
  o.y = (unsigned)f2bf(src[2 * 128]) | ((unsigned)f2bf(src[3 * 128]) << 16);
  o.z = (unsigned)f2bf(src[4 * 128]) | ((unsigned)f2bf(src[5 * 128]) << 16);
  o.w = (unsigned)f2bf(src[6 * 128]) | ((unsigned)f2bf(src[7 * 128]) << 16);
  *(uint4*)(W2t + (size_t)ng * 256 + k) = o;
}

// Wg [1280][8] f32 -> WgTb [16][1280] bf16 (rows 8..15 zero-pad)
__global__ __launch_bounds__(256) void pack_wg_kernel(const float* __restrict__ Wg,
                                                      unsigned short* __restrict__ WgTb) {
  int t = blockIdx.x * 256 + threadIdx.x;
  if (t >= 16 * 1280) return;
  int e = t / 1280, k = t - e * 1280;
  WgTb[t] = (e < 8) ? f2bf(Wg[(size_t)k * 8 + e]) : (unsigned short)0;
}

// ---------------- fused expert MLP (+gate on e==0 blocks) ----------------
// grid (8 experts, 1024 token-tiles of 64). 256 thr = 4 waves.
// Occupancy: register-bound fix. Accumulators = 100 f32/lane; without a cap
// the allocator kept acc1+acc2 disjoint (188 unified regs -> 2 waves/SIMD).
// __launch_bounds__(256,3) caps unified regs at 170 -> 3 blocks/CU; peak
// simultaneous need is ~115 regs (acc1 dead before acc2 lives), so no spill.
// LDS = 53248 B exactly -> 3 x 53248 = 159744 <= 160K.

__global__ __launch_bounds__(256, 3)
void expert_fused_kernel(const unsigned short* __restrict__ xb,
                         const unsigned short* __restrict__ W1t,
                         const float* __restrict__ b1,
                         const unsigned short* __restrict__ W2t,
                         const float* __restrict__ b2,
                         const float* __restrict__ W3,
                         const float* __restrict__ b3,
                         const unsigned short* __restrict__ WgTb,
                         const float* __restrict__ bg,
                         float* __restrict__ outG,
                         float* __restrict__ eo) {
  __shared__ __align__(16) unsigned short smem[26624];  // 53248 bytes exactly
  unsigned short* Ws  = smem;           // 8192 shorts
  unsigned short* Xs  = smem + 8192;    // 2048 shorts
  unsigned short* h1L = smem + 10240;   // 16384 shorts
  unsigned short* WgS = h1L;            // [16][32] overlay, phase-1 only

  const int tid = threadIdx.x;
  const int wv = tid >> 6;
  const int lane = tid & 63;
  const int e = blockIdx.x;
  const int m0 = blockIdx.y << 6;
  const bool gate_blk = (e == 0);

  const unsigned short* W1te = W1t + (size_t)e * 256 * 1280;
  const unsigned short* W2te = W2t + (size_t)e * 128 * 256;

  const int lr = lane >> 2;                                    // staging row-in-16
  const int ksw = ((lane & 3) ^ ((lane >> 3) & 3)) * 8;        // swizzled src k-offset
  const int fr = lane & 15;
  const int fkS = (((lane >> 4) ^ ((lane >> 1) & 3)) & 3) * 8; // swizzled frag slot
  const int fkL = (lane >> 4) * 8;                             // logical frag k-offset
  const int rq = (lane >> 4) * 4;

  const unsigned short* gx = xb + (size_t)(m0 + wv * 16 + lr) * 1280 + ksw;
  const unsigned short* gw = W1te + (size_t)(wv * 64 + lr) * 1280 + ksw;
  const unsigned short* gwg = WgTb + (size_t)lr * 1280 + ksw;
  unsigned short* lx = &Xs[(wv * 16) * 32];
  unsigned short* lw = &Ws[(wv * 64) * 32];
  const bool gate_stager = gate_blk && (wv == 0);

  // ---- phase 1: h1^T tile (256 hidden x 64 tokens), K=1280 ----
  floatx4 acc1[4][4] = {};
  floatx4 accg = {0.f, 0.f, 0.f, 0.f};
  for (int k0 = 0; k0 < 1280; k0 += 32) {
    GLDS16(gx + k0, lx);
    GLDS16(gw + k0, lw);
    GLDS16(gw + (size_t)16 * 1280 + k0, lw + 16 * 32);
    GLDS16(gw + (size_t)32 * 1280 + k0, lw + 32 * 32);
    GLDS16(gw + (size_t)48 * 1280 + k0, lw + 48 * 32);
    if (gate_stager) GLDS16(gwg + k0, WgS);
    __syncthreads();
    short8 bfv[4];
#pragma unroll
    for (int j = 0; j < 4; j++)
      bfv[j] = *(const short8*)&Xs[(j * 16 + fr) * 32 + fkS];
#pragma unroll
    for (int i = 0; i < 4; i++) {
      short8 af = *(const short8*)&Ws[(wv * 64 + i * 16 + fr) * 32 + fkS];
#pragma unroll
      for (int j = 0; j < 4; j++)
        acc1[i][j] = __builtin_amdgcn_mfma_f32_16x16x32_bf16(af, bfv[j], acc1[i][j], 0, 0, 0);
    }
    if (gate_blk) {
      short8 ag = *(const short8*)&WgS[fr * 32 + fkS];
      short8 bgf = *(const short8*)&Xs[(wv * 16 + fr) * 32 + fkS];  // j = wv group
      accg = __builtin_amdgcn_mfma_f32_16x16x32_bf16(ag, bgf, accg, 0, 0, 0);
    }
    __syncthreads();
  }

  // ---- gate epilogue (e==0 blocks): softmax over 8 experts, write outG ----
  // accg layout: col(lane&15)=token-in-group(wv), row((lane>>4)*4+r)=expert.
  if (gate_blk) {
    const int g = lane >> 4;
    float bg0 = 0.f, bg1 = 0.f, bg2 = 0.f, bg3 = 0.f;
    if (g < 2) {
      float4 t = *(const float4*)(bg + g * 4);
      bg0 = t.x; bg1 = t.y; bg2 = t.z; bg3 = t.w;
    }
    float v0 = accg[0] + bg0, v1 = accg[1] + bg1, v2 = accg[2] + bg2, v3 = accg[3] + bg3;
    float mx = fmaxf(fmaxf(v0, v1), fmaxf(v2, v3));
    mx = fmaxf(mx, __shfl_xor(mx, 16));  // pairs g0<->g1 (g2/g3 junk stays separate)
    float e0 = __expf(v0 - mx), e1 = __expf(v1 - mx), e2 = __expf(v2 - mx), e3 = __expf(v3 - mx);
    float s = e0 + e1 + e2 + e3;
    s += __shfl_xor(s, 16);
    float inv = 1.f / s;
    if (g < 2) {
      float4 o; o.x = e0 * inv; o.y = e1 * inv; o.z = e2 * inv; o.w = e3 * inv;
      *(float4*)&outG[(size_t)(m0 + wv * 16 + fr) * 8 + g * 4] = o;
    }
  }

  // ---- epilogue 1: relu(+b1), bf16, transpose into swizzled h1L[token][k] ----
#pragma unroll
  for (int i = 0; i < 4; i++) {
    const int rowb = wv * 64 + i * 16 + rq;  // hidden k-index base (4 consecutive)
    const float4 bb = *(const float4*)(b1 + e * 256 + rowb);  // L2-hot
#pragma unroll
    for (int j = 0; j < 4; j++) {
      float v0 = acc1[i][j][0] + bb.x; v0 = v0 > 0.f ? v0 : 0.f;
      float v1 = acc1[i][j][1] + bb.y; v1 = v1 > 0.f ? v1 : 0.f;
      float v2 = acc1[i][j][2] + bb.z; v2 = v2 > 0.f ? v2 : 0.f;
      float v3 = acc1[i][j][3] + bb.w; v3 = v3 > 0.f ? v3 : 0.f;
      uint2 pk;
      pk.x = (unsigned)f2bf(v0) | ((unsigned)f2bf(v1) << 16);
      pk.y = (unsigned)f2bf(v2) | ((unsigned)f2bf(v3) << 16);
      const int row = j * 16 + fr;  // token row
      *(uint2*)((char*)h1L + ((row * 512 + rowb * 2) ^ ((row & 7) << 4))) = pk;
    }
  }
  __syncthreads();

  // ---- phase 2: h2 tile (128 h2 x 64 tokens), K=256 ----
  floatx4 acc2[2][4] = {};
  const unsigned short* gw2 = W2te + (size_t)(wv * 32 + lr) * 256 + ksw;
  unsigned short* lw2 = &Ws[(wv * 32) * 32];
  for (int k0 = 0; k0 < 256; k0 += 32) {
    GLDS16(gw2 + k0, lw2);
    GLDS16(gw2 + 16 * 256 + k0, lw2 + 16 * 32);
    __syncthreads();
    short8 b2v[4];
#pragma unroll
    for (int j = 0; j < 4; j++) {
      const int row = j * 16 + fr;
      b2v[j] = *(const short8*)((const char*)h1L +
               ((row * 512 + (k0 + fkL) * 2) ^ ((row & 7) << 4)));
    }
#pragma unroll
    for (int i = 0; i < 2; i++) {
      short8 a2 = *(const short8*)&Ws[(wv * 32 + i * 16 + fr) * 32 + fkS];
#pragma unroll
      for (int j = 0; j < 4; j++)
        acc2[i][j] = __builtin_amdgcn_mfma_f32_16x16x32_bf16(a2, b2v[j], acc2[i][j], 0, 0, 0);
    }
    __syncthreads();
  }

  // ---- phase 3: expert_out = relu(h2+b2) . W3 ----
  float psum[4] = {0.f, 0.f, 0.f, 0.f};
#pragma unroll
  for (int i = 0; i < 2; i++) {
    const int rowb = wv * 32 + i * 16 + rq;  // h2 index base
    const float4 bb = *(const float4*)(b2 + e * 128 + rowb);
    const float4 ww = *(const float4*)(W3 + e * 128 + rowb);
    const float bba[4] = {bb.x, bb.y, bb.z, bb.w};
    const float wwa[4] = {ww.x, ww.y, ww.z, ww.w};
#pragma unroll
    for (int j = 0; j < 4; j++)
#pragma unroll
      for (int r = 0; r < 4; r++) {
        float v = acc2[i][j][r] + bba[r];
        v = v > 0.f ? v : 0.f;
        psum[j] += v * wwa[r];
      }
  }
#pragma unroll
  for (int j = 0; j < 4; j++) {
    float v = psum[j];
    v += __shfl_xor(v, 16);
    v += __shfl_xor(v, 32);
    psum[j] = v;
  }
  float* exS = (float*)Xs;  // Xs dead since phase 1
  if (lane < 16) {
#pragma unroll
    for (int j = 0; j < 4; j++) exS[wv * 64 + j * 16 + lane] = psum[j];
  }
  __syncthreads();
  if (tid < 64) {
    float tot = exS[tid] + exS[64 + tid] + exS[128 + tid] + exS[192 + tid];
    eo[(size_t)(m0 + tid) * 8 + e] = tot + b3[e];
  }
}

// ---------------- combine: predictions = sum(gate * eo) ----------------

__global__ __launch_bounds__(256)
void combine_kernel(const float* __restrict__ outG, const float* __restrict__ eo,
                    float* __restrict__ outP) {
  int t = blockIdx.x * 256 + threadIdx.x;
  const float4* g4 = (const float4*)(outG + (size_t)t * 8);
  const float4* e4 = (const float4*)(eo + (size_t)t * 8);
  float4 ga = g4[0], gb = g4[1], ea = e4[0], eb = e4[1];
  outP[t] = ga.x * ea.x + ga.y * ea.y + ga.z * ea.z + ga.w * ea.w +
            gb.x * eb.x + gb.y * eb.y + gb.z * eb.z + gb.w * eb.w;
}

// ---------------- launch ----------------

extern "C" void kernel_launch(void* const* d_in, const int* in_sizes, int n_in,
                              void* d_out, int out_size, void* d_ws, size_t ws_size,
                              hipStream_t stream) {
  const float* x  = (const float*)d_in[0];
  const float* W1 = (const float*)d_in[1];
  const float* b1 = (const float*)d_in[2];
  const float* W2 = (const float*)d_in[3];
  const float* b2 = (const float*)d_in[4];
  const float* W3 = (const float*)d_in[5];
  const float* b3 = (const float*)d_in[6];
  const float* Wg = (const float*)d_in[7];
  const float* bg = (const float*)d_in[8];
  float* outP = (float*)d_out;   // predictions [B] f32
  float* outG = outP + NTOK;     // gate [B][8] f32

  char* ws = (char*)d_ws;
  unsigned short* xb   = (unsigned short*)ws;                 // 167,772,160
  unsigned short* W1t  = (unsigned short*)(ws + 167772160ll); //   5,242,880
  unsigned short* W2t  = (unsigned short*)(ws + 173015040ll); //     524,288
  unsigned short* WgTb = (unsigned short*)(ws + 173539328ll); //      40,960
  float*          eo   = (float*)(ws + 173580288ll);          //   2,097,152  (tot ~175.7MB)

  cast_x_kernel<<<NTOK * KDIM / 4 / 256, 256, 0, stream>>>((const float4*)x, (uint2*)xb);
  pack_w1_kernel<<<1280, 256, 0, stream>>>(W1, W1t);
  pack_w2_kernel<<<128, 256, 0, stream>>>(W2, W2t);
  pack_wg_kernel<<<80, 256, 0, stream>>>(Wg, WgTb);

  expert_fused_kernel<<<dim3(8, 1024), 256, 0, stream>>>(xb, W1t, b1, W2t, b2, W3, b3,
                                                         WgTb, bg, outG, eo);
  combine_kernel<<<256, 256, 0, stream>>>(outG, eo, outP);
}

// Round 3
// 902.024 us; speedup vs baseline: 1.2148x; 1.1153x over previous
//
#include <hip/hip_runtime.h>
#include <stdint.h>

#define NTOK 65536
#define KDIM 1280

typedef __attribute__((ext_vector_type(8))) short short8;
typedef __attribute__((ext_vector_type(4))) float floatx4;

__device__ __forceinline__ unsigned short f2bf(float f) {
  union { float f; unsigned int u; } v; v.f = f;
  unsigned int r = v.u + 0x7FFFu + ((v.u >> 16) & 1u);  // RNE
  return (unsigned short)(r >> 16);
}

// async global->LDS, 16B per lane; lds base wave-uniform (HW adds lane*16)
#define GLDS16(gp, lp) \
  __builtin_amdgcn_global_load_lds((const __attribute__((address_space(1))) void*)(gp), \
                                   (__attribute__((address_space(3))) void*)(lp), 16, 0, 0)

// ---------------- prep kernels ----------------

__global__ __launch_bounds__(256) void cast_x_kernel(const float4* __restrict__ x,
                                                     uint2* __restrict__ xb) {
  size_t i = (size_t)blockIdx.x * 256 + threadIdx.x;
  float4 v = x[i];
  uint2 o;
  o.x = (unsigned)f2bf(v.x) | ((unsigned)f2bf(v.y) << 16);
  o.y = (unsigned)f2bf(v.z) | ((unsigned)f2bf(v.w) << 16);
  xb[i] = o;
}

// W1 [E][1280][256] f32 -> W1t [n=e*256+h][k] bf16
__global__ __launch_bounds__(256) void pack_w1_kernel(const float* __restrict__ W1,
                                                      unsigned short* __restrict__ W1t) {
  int t = blockIdx.x * 256 + threadIdx.x;
  if (t >= 2048 * 160) return;
  int n = t / 160, kg = t - n * 160;
  int e = n >> 8, h = n & 255;
  int k = kg * 8;
  const float* src = W1 + ((size_t)e * 1280 + k) * 256 + h;
  uint4 o;
  o.x = (unsigned)f2bf(src[0])       | ((unsigned)f2bf(src[256])     << 16);
  o.y = (unsigned)f2bf(src[2 * 256]) | ((unsigned)f2bf(src[3 * 256]) << 16);
  o.z = (unsigned)f2bf(src[4 * 256]) | ((unsigned)f2bf(src[5 * 256]) << 16);
  o.w = (unsigned)f2bf(src[6 * 256]) | ((unsigned)f2bf(src[7 * 256]) << 16);
  *(uint4*)(W1t + (size_t)n * 1280 + k) = o;
}

// W2 [E][256][128] f32 -> W2t [e][n=0..127][k=0..255] bf16
__global__ __launch_bounds__(256) void pack_w2_kernel(const float* __restrict__ W2,
                                                      unsigned short* __restrict__ W2t) {
  int t = blockIdx.x * 256 + threadIdx.x;
  if (t >= 1024 * 32) return;
  int ng = t >> 5, kg = t & 31;
  int e = ng >> 7, n = ng & 127;
  int k = kg * 8;
  const float* src = W2 + (size_t)e * 32768 + (size_t)k * 128 + n;
  uint4 o;
  o.x = (unsigned)f2bf(src[0])       | ((unsigned)f2bf(src[128])     << 16);
  o.y = (unsigned)f2bf(src[2 * 128]) | ((unsigned)f2bf(src[3 * 128]) << 16);
  o.z = (unsigned)f2bf(src[4 * 128]) | ((unsigned)f2bf(src[5 * 128]) << 16);
  o.w = (unsigned)f2bf(src[6 * 128]) | ((unsigned)f2bf(src[7 * 128]) << 16);
  *(uint4*)(W2t + (size_t)ng * 256 + k) = o;
}

// Wg [1280][8] f32 -> WgTb [16][1280] bf16 (rows 8..15 zero-pad)
__global__ __launch_bounds__(256) void pack_wg_kernel(const float* __restrict__ Wg,
                                                      unsigned short* __restrict__ WgTb) {
  int t = blockIdx.x * 256 + threadIdx.x;
  if (t >= 16 * 1280) return;
  int e = t / 1280, k = t - e * 1280;
  WgTb[t] = (e < 8) ? f2bf(Wg[(size_t)k * 8 + e]) : (unsigned short)0;
}

// ---------------- fused expert MLP (+gate on e==0 blocks) ----------------
// grid (8 experts, 1024 token-tiles of 64). 256 thr = 4 waves.
// BK=64: two 32-k slabs per barrier pair -> 24 barrier-pairs/block (was 48).
// Each drain costs the same; MFMA per drain doubles. LDS pool 49152 B via
// time-disjoint aliasing (h1L over WsA+WsB; W2 slabs over Xs; WgS over W2B)
// -> 3 blocks/CU with __launch_bounds__(256,3) register cap (proven r2: no spill).

__global__ __launch_bounds__(256, 3)
void expert_fused_kernel(const unsigned short* __restrict__ xb,
                         const unsigned short* __restrict__ W1t,
                         const float* __restrict__ b1,
                         const unsigned short* __restrict__ W2t,
                         const float* __restrict__ b2,
                         const float* __restrict__ W3,
                         const float* __restrict__ b3,
                         const unsigned short* __restrict__ WgTb,
                         const float* __restrict__ bg,
                         float* __restrict__ outG,
                         float* __restrict__ eo) {
  __shared__ __align__(16) unsigned short smem[24576];  // 49152 bytes
  unsigned short* WsA = smem;            // [256][32] phase 1 slab A
  unsigned short* WsB = smem + 8192;     // [256][32] phase 1 slab B
  unsigned short* XsA = smem + 16384;    // [64][32]
  unsigned short* XsB = smem + 18432;    // [64][32]
  unsigned short* h1L = smem;            // [64][256] swizzled; aliases WsA/WsB (post phase 1)
  unsigned short* W2A = smem + 16384;    // [128][32] phase 2; aliases XsA/XsB
  unsigned short* W2B = smem + 20480;    // [128][32] phase 2
  unsigned short* WgA = smem + 20480;    // [16][32] phase 1 only (aliases W2B, time-disjoint)
  unsigned short* WgB = smem + 21504;    // [16][32]

  const int tid = threadIdx.x;
  const int wv = tid >> 6;
  const int lane = tid & 63;
  const int e = blockIdx.x;
  const int m0 = blockIdx.y << 6;
  const bool gate_blk = (e == 0);

  const unsigned short* W1te = W1t + (size_t)e * 256 * 1280;
  const unsigned short* W2te = W2t + (size_t)e * 128 * 256;

  const int lr = lane >> 2;                                    // staging row-in-16
  const int ksw = ((lane & 3) ^ ((lane >> 3) & 3)) * 8;        // swizzled src k-offset
  const int fr = lane & 15;
  const int fkS = (((lane >> 4) ^ ((lane >> 1) & 3)) & 3) * 8; // swizzled frag slot
  const int fkL = (lane >> 4) * 8;                             // logical frag k-offset
  const int rq = (lane >> 4) * 4;

  const unsigned short* gx = xb + (size_t)(m0 + wv * 16 + lr) * 1280 + ksw;
  const unsigned short* gw = W1te + (size_t)(wv * 64 + lr) * 1280 + ksw;
  const unsigned short* gwg = WgTb + (size_t)lr * 1280 + ksw;
  unsigned short* lxA = &XsA[(wv * 16) * 32];
  unsigned short* lxB = &XsB[(wv * 16) * 32];
  unsigned short* lwA = &WsA[(wv * 64) * 32];
  unsigned short* lwB = &WsB[(wv * 64) * 32];
  const bool gate_stager = gate_blk && (wv == 0);

  // ---- phase 1: h1^T tile (256 hidden x 64 tokens), K=1280, BK=64 ----
  floatx4 acc1[4][4] = {};
  floatx4 accg = {0.f, 0.f, 0.f, 0.f};
  for (int k0 = 0; k0 < 1280; k0 += 64) {
    GLDS16(gx + k0, lxA);
    GLDS16(gx + k0 + 32, lxB);
#pragma unroll
    for (int r = 0; r < 4; r++) {
      GLDS16(gw + (size_t)(16 * r) * 1280 + k0, lwA + r * 16 * 32);
      GLDS16(gw + (size_t)(16 * r) * 1280 + k0 + 32, lwB + r * 16 * 32);
    }
    if (gate_stager) { GLDS16(gwg + k0, WgA); GLDS16(gwg + k0 + 32, WgB); }
    __syncthreads();
    // slab A
    {
      short8 bfv[4];
#pragma unroll
      for (int j = 0; j < 4; j++)
        bfv[j] = *(const short8*)&XsA[(j * 16 + fr) * 32 + fkS];
#pragma unroll
      for (int i = 0; i < 4; i++) {
        short8 af = *(const short8*)&WsA[(wv * 64 + i * 16 + fr) * 32 + fkS];
#pragma unroll
        for (int j = 0; j < 4; j++)
          acc1[i][j] = __builtin_amdgcn_mfma_f32_16x16x32_bf16(af, bfv[j], acc1[i][j], 0, 0, 0);
      }
      if (gate_blk) {
        short8 ag = *(const short8*)&WgA[fr * 32 + fkS];
        short8 bgf = *(const short8*)&XsA[(wv * 16 + fr) * 32 + fkS];
        accg = __builtin_amdgcn_mfma_f32_16x16x32_bf16(ag, bgf, accg, 0, 0, 0);
      }
    }
    // slab B
    {
      short8 bfv[4];
#pragma unroll
      for (int j = 0; j < 4; j++)
        bfv[j] = *(const short8*)&XsB[(j * 16 + fr) * 32 + fkS];
#pragma unroll
      for (int i = 0; i < 4; i++) {
        short8 af = *(const short8*)&WsB[(wv * 64 + i * 16 + fr) * 32 + fkS];
#pragma unroll
        for (int j = 0; j < 4; j++)
          acc1[i][j] = __builtin_amdgcn_mfma_f32_16x16x32_bf16(af, bfv[j], acc1[i][j], 0, 0, 0);
      }
      if (gate_blk) {
        short8 ag = *(const short8*)&WgB[fr * 32 + fkS];
        short8 bgf = *(const short8*)&XsB[(wv * 16 + fr) * 32 + fkS];
        accg = __builtin_amdgcn_mfma_f32_16x16x32_bf16(ag, bgf, accg, 0, 0, 0);
      }
    }
    __syncthreads();
  }

  // ---- gate epilogue (e==0 blocks): softmax over 8 experts, write outG ----
  // accg layout: col(lane&15)=token-in-group(wv), row((lane>>4)*4+r)=expert.
  if (gate_blk) {
    const int g = lane >> 4;
    float bg0 = 0.f, bg1 = 0.f, bg2 = 0.f, bg3 = 0.f;
    if (g < 2) {
      float4 t = *(const float4*)(bg + g * 4);
      bg0 = t.x; bg1 = t.y; bg2 = t.z; bg3 = t.w;
    }
    float v0 = accg[0] + bg0, v1 = accg[1] + bg1, v2 = accg[2] + bg2, v3 = accg[3] + bg3;
    float mx = fmaxf(fmaxf(v0, v1), fmaxf(v2, v3));
    mx = fmaxf(mx, __shfl_xor(mx, 16));  // pairs g0<->g1 (g2/g3 junk stays separate)
    float e0 = __expf(v0 - mx), e1 = __expf(v1 - mx), e2 = __expf(v2 - mx), e3 = __expf(v3 - mx);
    float s = e0 + e1 + e2 + e3;
    s += __shfl_xor(s, 16);
    float inv = 1.f / s;
    if (g < 2) {
      float4 o; o.x = e0 * inv; o.y = e1 * inv; o.z = e2 * inv; o.w = e3 * inv;
      *(float4*)&outG[(size_t)(m0 + wv * 16 + fr) * 8 + g * 4] = o;
    }
  }

  // ---- epilogue 1: relu(+b1), bf16, transpose into swizzled h1L[token][k] ----
  // h1L aliases WsA/WsB: safe, all Ws reads completed at the loop-tail barrier.
#pragma unroll
  for (int i = 0; i < 4; i++) {
    const int rowb = wv * 64 + i * 16 + rq;  // hidden k-index base (4 consecutive)
    const float4 bb = *(const float4*)(b1 + e * 256 + rowb);  // L2-hot
#pragma unroll
    for (int j = 0; j < 4; j++) {
      float v0 = acc1[i][j][0] + bb.x; v0 = v0 > 0.f ? v0 : 0.f;
      float v1 = acc1[i][j][1] + bb.y; v1 = v1 > 0.f ? v1 : 0.f;
      float v2 = acc1[i][j][2] + bb.z; v2 = v2 > 0.f ? v2 : 0.f;
      float v3 = acc1[i][j][3] + bb.w; v3 = v3 > 0.f ? v3 : 0.f;
      uint2 pk;
      pk.x = (unsigned)f2bf(v0) | ((unsigned)f2bf(v1) << 16);
      pk.y = (unsigned)f2bf(v2) | ((unsigned)f2bf(v3) << 16);
      const int row = j * 16 + fr;  // token row
      *(uint2*)((char*)h1L + ((row * 512 + rowb * 2) ^ ((row & 7) << 4))) = pk;
    }
  }
  __syncthreads();

  // ---- phase 2: h2 tile (128 h2 x 64 tokens), K=256, BK=64 ----
  floatx4 acc2[2][4] = {};
  const unsigned short* gw2 = W2te + (size_t)(wv * 32 + lr) * 256 + ksw;
  unsigned short* lw2A = &W2A[(wv * 32) * 32];
  unsigned short* lw2B = &W2B[(wv * 32) * 32];
  for (int k0 = 0; k0 < 256; k0 += 64) {
    GLDS16(gw2 + k0, lw2A);
    GLDS16(gw2 + 16 * 256 + k0, lw2A + 16 * 32);
    GLDS16(gw2 + k0 + 32, lw2B);
    GLDS16(gw2 + 16 * 256 + k0 + 32, lw2B + 16 * 32);
    __syncthreads();
#pragma unroll
    for (int h = 0; h < 2; h++) {
      const unsigned short* W2s = h ? W2B : W2A;
      const int kk = k0 + h * 32;
      short8 b2v[4];
#pragma unroll
      for (int j = 0; j < 4; j++) {
        const int row = j * 16 + fr;
        b2v[j] = *(const short8*)((const char*)h1L +
                 ((row * 512 + (kk + fkL) * 2) ^ ((row & 7) << 4)));
      }
#pragma unroll
      for (int i = 0; i < 2; i++) {
        short8 a2 = *(const short8*)&W2s[(wv * 32 + i * 16 + fr) * 32 + fkS];
#pragma unroll
        for (int j = 0; j < 4; j++)
          acc2[i][j] = __builtin_amdgcn_mfma_f32_16x16x32_bf16(a2, b2v[j], acc2[i][j], 0, 0, 0);
      }
    }
    __syncthreads();
  }

  // ---- phase 3: expert_out = relu(h2+b2) . W3 ----
  float psum[4] = {0.f, 0.f, 0.f, 0.f};
#pragma unroll
  for (int i = 0; i < 2; i++) {
    const int rowb = wv * 32 + i * 16 + rq;  // h2 index base
    const float4 bb = *(const float4*)(b2 + e * 128 + rowb);
    const float4 ww = *(const float4*)(W3 + e * 128 + rowb);
    const float bba[4] = {bb.x, bb.y, bb.z, bb.w};
    const float wwa[4] = {ww.x, ww.y, ww.z, ww.w};
#pragma unroll
    for (int j = 0; j < 4; j++)
#pragma unroll
      for (int r = 0; r < 4; r++) {
        float v = acc2[i][j][r] + bba[r];
        v = v > 0.f ? v : 0.f;
        psum[j] += v * wwa[r];
      }
  }
#pragma unroll
  for (int j = 0; j < 4; j++) {
    float v = psum[j];
    v += __shfl_xor(v, 16);
    v += __shfl_xor(v, 32);
    psum[j] = v;
  }
  float* exS = (float*)XsA;  // aliases W2A; safe after phase-2 tail barrier
  if (lane < 16) {
#pragma unroll
    for (int j = 0; j < 4; j++) exS[wv * 64 + j * 16 + lane] = psum[j];
  }
  __syncthreads();
  if (tid < 64) {
    float tot = exS[tid] + exS[64 + tid] + exS[128 + tid] + exS[192 + tid];
    eo[(size_t)(m0 + tid) * 8 + e] = tot + b3[e];
  }
}

// ---------------- combine: predictions = sum(gate * eo) ----------------

__global__ __launch_bounds__(256)
void combine_kernel(const float* __restrict__ outG, const float* __restrict__ eo,
                    float* __restrict__ outP) {
  int t = blockIdx.x * 256 + threadIdx.x;
  const float4* g4 = (const float4*)(outG + (size_t)t * 8);
  const float4* e4 = (const float4*)(eo + (size_t)t * 8);
  float4 ga = g4[0], gb = g4[1], ea = e4[0], eb = e4[1];
  outP[t] = ga.x * ea.x + ga.y * ea.y + ga.z * ea.z + ga.w * ea.w +
            gb.x * eb.x + gb.y * eb.y + gb.z * eb.z + gb.w * eb.w;
}

// ---------------- launch ----------------

extern "C" void kernel_launch(void* const* d_in, const int* in_sizes, int n_in,
                              void* d_out, int out_size, void* d_ws, size_t ws_size,
                              hipStream_t stream) {
  const float* x  = (const float*)d_in[0];
  const float* W1 = (const float*)d_in[1];
  const float* b1 = (const float*)d_in[2];
  const float* W2 = (const float*)d_in[3];
  const float* b2 = (const float*)d_in[4];
  const float* W3 = (const float*)d_in[5];
  const float* b3 = (const float*)d_in[6];
  const float* Wg = (const float*)d_in[7];
  const float* bg = (const float*)d_in[8];
  float* outP = (float*)d_out;   // predictions [B] f32
  float* outG = outP + NTOK;     // gate [B][8] f32

  char* ws = (char*)d_ws;
  unsigned short* xb   = (unsigned short*)ws;                 // 167,772,160
  unsigned short* W1t  = (unsigned short*)(ws + 167772160ll); //   5,242,880
  unsigned short* W2t  = (unsigned short*)(ws + 173015040ll); //     524,288
  unsigned short* WgTb = (unsigned short*)(ws + 173539328ll); //      40,960
  float*          eo   = (float*)(ws + 173580288ll);          //   2,097,152  (tot ~175.7MB)

  cast_x_kernel<<<NTOK * KDIM / 4 / 256, 256, 0, stream>>>((const float4*)x, (uint2*)xb);
  pack_w1_kernel<<<1280, 256, 0, stream>>>(W1, W1t);
  pack_w2_kernel<<<128, 256, 0, stream>>>(W2, W2t);
  pack_wg_kernel<<<80, 256, 0, stream>>>(Wg, WgTb);

  expert_fused_kernel<<<dim3(8, 1024), 256, 0, stream>>>(xb, W1t, b1, W2t, b2, W3, b3,
                                                         WgTb, bg, outG, eo);
  combine_kernel<<<256, 256, 0, stream>>>(outG, eo, outP);
}

// Round 4
// 890.417 us; speedup vs baseline: 1.2307x; 1.0130x over previous
//
#include <hip/hip_runtime.h>
#include <stdint.h>

#define NTOK 65536
#define KDIM 1280

typedef __attribute__((ext_vector_type(8))) short short8;
typedef __attribute__((ext_vector_type(4))) float floatx4;

__device__ __forceinline__ unsigned short f2bf(float f) {
  union { float f; unsigned int u; } v; v.f = f;
  unsigned int r = v.u + 0x7FFFu + ((v.u >> 16) & 1u);  // RNE
  return (unsigned short)(r >> 16);
}

// packed f32x2 -> bf16x2 (RNE), single HW instruction
__device__ __forceinline__ unsigned cvtpk(float lo, float hi) {
  unsigned r;
  asm("v_cvt_pk_bf16_f32 %0, %1, %2" : "=v"(r) : "v"(lo), "v"(hi));
  return r;
}

// async global->LDS, 16B per lane; lds base wave-uniform (HW adds lane*16)
#define GLDS16(gp, lp) \
  __builtin_amdgcn_global_load_lds((const __attribute__((address_space(1))) void*)(gp), \
                                   (__attribute__((address_space(3))) void*)(lp), 16, 0, 0)

// ---------------- merged pack kernel (W1, W2, Wg) ----------------
// 380,928 threads = 1488 blocks x 256 exactly.

__global__ __launch_bounds__(256)
void pack_all_kernel(const float* __restrict__ W1, const float* __restrict__ W2,
                     const float* __restrict__ Wg,
                     unsigned short* __restrict__ W1t, unsigned short* __restrict__ W2t,
                     unsigned short* __restrict__ WgTb) {
  int t = blockIdx.x * 256 + threadIdx.x;
  if (t < 327680) {  // W1 [E][1280][256] -> W1t [n=e*256+h][k]
    int n = t / 160, kg = t - n * 160;
    int e = n >> 8, h = n & 255;
    int k = kg * 8;
    const float* src = W1 + ((size_t)e * 1280 + k) * 256 + h;
    uint4 o;
    o.x = (unsigned)f2bf(src[0])       | ((unsigned)f2bf(src[256])     << 16);
    o.y = (unsigned)f2bf(src[2 * 256]) | ((unsigned)f2bf(src[3 * 256]) << 16);
    o.z = (unsigned)f2bf(src[4 * 256]) | ((unsigned)f2bf(src[5 * 256]) << 16);
    o.w = (unsigned)f2bf(src[6 * 256]) | ((unsigned)f2bf(src[7 * 256]) << 16);
    *(uint4*)(W1t + (size_t)n * 1280 + k) = o;
  } else if (t < 360448) {  // W2 [E][256][128] -> W2t [e*128+n][k]
    int t2 = t - 327680;
    int ng = t2 >> 5, kg = t2 & 31;
    int e = ng >> 7, n = ng & 127;
    int k = kg * 8;
    const float* src = W2 + (size_t)e * 32768 + (size_t)k * 128 + n;
    uint4 o;
    o.x = (unsigned)f2bf(src[0])       | ((unsigned)f2bf(src[128])     << 16);
    o.y = (unsigned)f2bf(src[2 * 128]) | ((unsigned)f2bf(src[3 * 128]) << 16);
    o.z = (unsigned)f2bf(src[4 * 128]) | ((unsigned)f2bf(src[5 * 128]) << 16);
    o.w = (unsigned)f2bf(src[6 * 128]) | ((unsigned)f2bf(src[7 * 128]) << 16);
    *(uint4*)(W2t + (size_t)ng * 256 + k) = o;
  } else {  // Wg [1280][8] -> WgTb [16][1280] (rows 8..15 zero)
    int t3 = t - 360448;
    int e = t3 / 1280, k = t3 - e * 1280;
    WgTb[t3] = (e < 8) ? f2bf(Wg[(size_t)k * 8 + e]) : (unsigned short)0;
  }
}

// ---------------- fused expert MLP (+gate on e==0 blocks) ----------------
// grid (8,1024) = 8192 blocks, remapped so each XCD (wg&7) owns a contiguous
// 128-tile range x all 8 experts (experts fastest): xb tile fetched once/XCD,
// all experts' weights L2-resident. Bijective: c=wg&7,w=wg>>3 -> e=w&7,
// tile=c*128+(w>>3).
// x is read directly as f32 and cast in-register (cvt_pk_bf16) into LDS,
// replicating the GLDS16 swizzled-src/linear-dst mapping -> cast_x deleted.
// BK=64, LDS 49152 B, __launch_bounds__(256,3) -> 3 blocks/CU (r2/r3 proven).

__global__ __launch_bounds__(256, 3)
void expert_fused_kernel(const float* __restrict__ xf,
                         const unsigned short* __restrict__ W1t,
                         const float* __restrict__ b1,
                         const unsigned short* __restrict__ W2t,
                         const float* __restrict__ b2,
                         const float* __restrict__ W3,
                         const float* __restrict__ b3,
                         const unsigned short* __restrict__ WgTb,
                         const float* __restrict__ bg,
                         float* __restrict__ outG,
                         float* __restrict__ eo) {
  __shared__ __align__(16) unsigned short smem[24576];  // 49152 bytes
  unsigned short* WsA = smem;            // [256][32] phase 1 slab A
  unsigned short* WsB = smem + 8192;     // [256][32] phase 1 slab B
  unsigned short* XsA = smem + 16384;    // [64][32]
  unsigned short* XsB = smem + 18432;    // [64][32]
  unsigned short* h1L = smem;            // [64][256] swizzled; aliases WsA/WsB (post phase 1)
  unsigned short* W2A = smem + 16384;    // [128][32] phase 2; aliases XsA/XsB
  unsigned short* W2B = smem + 20480;    // [128][32] phase 2
  unsigned short* WgA = smem + 20480;    // [16][32] phase 1 only (aliases W2B, time-disjoint)
  unsigned short* WgB = smem + 21504;    // [16][32]

  const int tid = threadIdx.x;
  const int wv = tid >> 6;
  const int lane = tid & 63;

  // XCD-grouped remap (bijective over 8192 blocks)
  const int wg = blockIdx.x + (blockIdx.y << 3);  // dispatch-linear, x fastest
  const int c  = wg & 7;                          // XCD (round-robin heuristic)
  const int w  = wg >> 3;                         // per-XCD sequence
  const int e  = w & 7;                           // expert (fastest within tile)
  const int m0 = ((c << 7) + (w >> 3)) << 6;      // token tile base
  const bool gate_blk = (e == 0);

  const unsigned short* W1te = W1t + (size_t)e * 256 * 1280;
  const unsigned short* W2te = W2t + (size_t)e * 128 * 256;

  const int lr = lane >> 2;                                    // staging row-in-16
  const int ksw = ((lane & 3) ^ ((lane >> 3) & 3)) * 8;        // swizzled src k-offset
  const int fr = lane & 15;
  const int fkS = (((lane >> 4) ^ ((lane >> 1) & 3)) & 3) * 8; // swizzled frag slot
  const int fkL = (lane >> 4) * 8;                             // logical frag k-offset
  const int rq = (lane >> 4) * 4;

  const float* gxf = xf + (size_t)(m0 + wv * 16 + lr) * 1280 + ksw;
  const unsigned short* gw = W1te + (size_t)(wv * 64 + lr) * 1280 + ksw;
  const unsigned short* gwg = WgTb + (size_t)lr * 1280 + ksw;
  unsigned short* lwA = &WsA[(wv * 64) * 32];
  unsigned short* lwB = &WsB[(wv * 64) * 32];
  const bool gate_stager = gate_blk && (wv == 0);

  // ---- phase 1: h1^T tile (256 hidden x 64 tokens), K=1280, BK=64 ----
  floatx4 acc1[4][4] = {};
  floatx4 accg = {0.f, 0.f, 0.f, 0.f};
  for (int k0 = 0; k0 < 1280; k0 += 64) {
    // x: f32 loads (swizzled k like the old GLDS16 source), cast later
    float4 xa0 = *(const float4*)(gxf + k0);
    float4 xa1 = *(const float4*)(gxf + k0 + 4);
    float4 xb0 = *(const float4*)(gxf + k0 + 32);
    float4 xb1 = *(const float4*)(gxf + k0 + 36);
#pragma unroll
    for (int r = 0; r < 4; r++) {
      GLDS16(gw + (size_t)(16 * r) * 1280 + k0, lwA + r * 16 * 32);
      GLDS16(gw + (size_t)(16 * r) * 1280 + k0 + 32, lwB + r * 16 * 32);
    }
    if (gate_stager) { GLDS16(gwg + k0, WgA); GLDS16(gwg + k0 + 32, WgB); }
    // cast + LDS write to the exact slot GLDS16 used: row wv*16+lr, col (lane&3)*8
    uint4 pa, pb;
    pa.x = cvtpk(xa0.x, xa0.y); pa.y = cvtpk(xa0.z, xa0.w);
    pa.z = cvtpk(xa1.x, xa1.y); pa.w = cvtpk(xa1.z, xa1.w);
    pb.x = cvtpk(xb0.x, xb0.y); pb.y = cvtpk(xb0.z, xb0.w);
    pb.z = cvtpk(xb1.x, xb1.y); pb.w = cvtpk(xb1.z, xb1.w);
    *(uint4*)&XsA[(wv * 16 + lr) * 32 + (lane & 3) * 8] = pa;
    *(uint4*)&XsB[(wv * 16 + lr) * 32 + (lane & 3) * 8] = pb;
    __syncthreads();
    // slab A
    {
      short8 bfv[4];
#pragma unroll
      for (int j = 0; j < 4; j++)
        bfv[j] = *(const short8*)&XsA[(j * 16 + fr) * 32 + fkS];
#pragma unroll
      for (int i = 0; i < 4; i++) {
        short8 af = *(const short8*)&WsA[(wv * 64 + i * 16 + fr) * 32 + fkS];
#pragma unroll
        for (int j = 0; j < 4; j++)
          acc1[i][j] = __builtin_amdgcn_mfma_f32_16x16x32_bf16(af, bfv[j], acc1[i][j], 0, 0, 0);
      }
      if (gate_blk) {
        short8 ag = *(const short8*)&WgA[fr * 32 + fkS];
        short8 bgf = *(const short8*)&XsA[(wv * 16 + fr) * 32 + fkS];
        accg = __builtin_amdgcn_mfma_f32_16x16x32_bf16(ag, bgf, accg, 0, 0, 0);
      }
    }
    // slab B
    {
      short8 bfv[4];
#pragma unroll
      for (int j = 0; j < 4; j++)
        bfv[j] = *(const short8*)&XsB[(j * 16 + fr) * 32 + fkS];
#pragma unroll
      for (int i = 0; i < 4; i++) {
        short8 af = *(const short8*)&WsB[(wv * 64 + i * 16 + fr) * 32 + fkS];
#pragma unroll
        for (int j = 0; j < 4; j++)
          acc1[i][j] = __builtin_amdgcn_mfma_f32_16x16x32_bf16(af, bfv[j], acc1[i][j], 0, 0, 0);
      }
      if (gate_blk) {
        short8 ag = *(const short8*)&WgB[fr * 32 + fkS];
        short8 bgf = *(const short8*)&XsB[(wv * 16 + fr) * 32 + fkS];
        accg = __builtin_amdgcn_mfma_f32_16x16x32_bf16(ag, bgf, accg, 0, 0, 0);
      }
    }
    __syncthreads();
  }

  // ---- gate epilogue (e==0 blocks): softmax over 8 experts, write outG ----
  // accg layout: col(lane&15)=token-in-group(wv), row((lane>>4)*4+r)=expert.
  if (gate_blk) {
    const int g = lane >> 4;
    float bg0 = 0.f, bg1 = 0.f, bg2 = 0.f, bg3 = 0.f;
    if (g < 2) {
      float4 t = *(const float4*)(bg + g * 4);
      bg0 = t.x; bg1 = t.y; bg2 = t.z; bg3 = t.w;
    }
    float v0 = accg[0] + bg0, v1 = accg[1] + bg1, v2 = accg[2] + bg2, v3 = accg[3] + bg3;
    float mx = fmaxf(fmaxf(v0, v1), fmaxf(v2, v3));
    mx = fmaxf(mx, __shfl_xor(mx, 16));  // pairs g0<->g1 (g2/g3 junk stays separate)
    float e0 = __expf(v0 - mx), e1 = __expf(v1 - mx), e2 = __expf(v2 - mx), e3 = __expf(v3 - mx);
    float s = e0 + e1 + e2 + e3;
    s += __shfl_xor(s, 16);
    float inv = 1.f / s;
    if (g < 2) {
      float4 o; o.x = e0 * inv; o.y = e1 * inv; o.z = e2 * inv; o.w = e3 * inv;
      *(float4*)&outG[(size_t)(m0 + wv * 16 + fr) * 8 + g * 4] = o;
    }
  }

  // ---- epilogue 1: relu(+b1), bf16, transpose into swizzled h1L[token][k] ----
  // h1L aliases WsA/WsB: safe, all Ws reads completed at the loop-tail barrier.
#pragma unroll
  for (int i = 0; i < 4; i++) {
    const int rowb = wv * 64 + i * 16 + rq;  // hidden k-index base (4 consecutive)
    const float4 bb = *(const float4*)(b1 + e * 256 + rowb);  // L2-hot
#pragma unroll
    for (int j = 0; j < 4; j++) {
      float v0 = acc1[i][j][0] + bb.x; v0 = v0 > 0.f ? v0 : 0.f;
      float v1 = acc1[i][j][1] + bb.y; v1 = v1 > 0.f ? v1 : 0.f;
      float v2 = acc1[i][j][2] + bb.z; v2 = v2 > 0.f ? v2 : 0.f;
      float v3 = acc1[i][j][3] + bb.w; v3 = v3 > 0.f ? v3 : 0.f;
      uint2 pk;
      pk.x = (unsigned)f2bf(v0) | ((unsigned)f2bf(v1) << 16);
      pk.y = (unsigned)f2bf(v2) | ((unsigned)f2bf(v3) << 16);
      const int row = j * 16 + fr;  // token row
      *(uint2*)((char*)h1L + ((row * 512 + rowb * 2) ^ ((row & 7) << 4))) = pk;
    }
  }
  __syncthreads();

  // ---- phase 2: h2 tile (128 h2 x 64 tokens), K=256, BK=64 ----
  floatx4 acc2[2][4] = {};
  const unsigned short* gw2 = W2te + (size_t)(wv * 32 + lr) * 256 + ksw;
  unsigned short* lw2A = &W2A[(wv * 32) * 32];
  unsigned short* lw2B = &W2B[(wv * 32) * 32];
  for (int k0 = 0; k0 < 256; k0 += 64) {
    GLDS16(gw2 + k0, lw2A);
    GLDS16(gw2 + 16 * 256 + k0, lw2A + 16 * 32);
    GLDS16(gw2 + k0 + 32, lw2B);
    GLDS16(gw2 + 16 * 256 + k0 + 32, lw2B + 16 * 32);
    __syncthreads();
#pragma unroll
    for (int h = 0; h < 2; h++) {
      const unsigned short* W2s = h ? W2B : W2A;
      const int kk = k0 + h * 32;
      short8 b2v[4];
#pragma unroll
      for (int j = 0; j < 4; j++) {
        const int row = j * 16 + fr;
        b2v[j] = *(const short8*)((const char*)h1L +
                 ((row * 512 + (kk + fkL) * 2) ^ ((row & 7) << 4)));
      }
#pragma unroll
      for (int i = 0; i < 2; i++) {
        short8 a2 = *(const short8*)&W2s[(wv * 32 + i * 16 + fr) * 32 + fkS];
#pragma unroll
        for (int j = 0; j < 4; j++)
          acc2[i][j] = __builtin_amdgcn_mfma_f32_16x16x32_bf16(a2, b2v[j], acc2[i][j], 0, 0, 0);
      }
    }
    __syncthreads();
  }

  // ---- phase 3: expert_out = relu(h2+b2) . W3 ----
  float psum[4] = {0.f, 0.f, 0.f, 0.f};
#pragma unroll
  for (int i = 0; i < 2; i++) {
    const int rowb = wv * 32 + i * 16 + rq;  // h2 index base
    const float4 bb = *(const float4*)(b2 + e * 128 + rowb);
    const float4 ww = *(const float4*)(W3 + e * 128 + rowb);
    const float bba[4] = {bb.x, bb.y, bb.z, bb.w};
    const float wwa[4] = {ww.x, ww.y, ww.z, ww.w};
#pragma unroll
    for (int j = 0; j < 4; j++)
#pragma unroll
      for (int r = 0; r < 4; r++) {
        float v = acc2[i][j][r] + bba[r];
        v = v > 0.f ? v : 0.f;
        psum[j] += v * wwa[r];
      }
  }
#pragma unroll
  for (int j = 0; j < 4; j++) {
    float v = psum[j];
    v += __shfl_xor(v, 16);
    v += __shfl_xor(v, 32);
    psum[j] = v;
  }
  float* exS = (float*)XsA;  // aliases W2A; safe after phase-2 tail barrier
  if (lane < 16) {
#pragma unroll
    for (int j = 0; j < 4; j++) exS[wv * 64 + j * 16 + lane] = psum[j];
  }
  __syncthreads();
  if (tid < 64) {
    float tot = exS[tid] + exS[64 + tid] + exS[128 + tid] + exS[192 + tid];
    eo[(size_t)(m0 + tid) * 8 + e] = tot + b3[e];
  }
}

// ---------------- combine: predictions = sum(gate * eo) ----------------

__global__ __launch_bounds__(256)
void combine_kernel(const float* __restrict__ outG, const float* __restrict__ eo,
                    float* __restrict__ outP) {
  int t = blockIdx.x * 256 + threadIdx.x;
  const float4* g4 = (const float4*)(outG + (size_t)t * 8);
  const float4* e4 = (const float4*)(eo + (size_t)t * 8);
  float4 ga = g4[0], gb = g4[1], ea = e4[0], eb = e4[1];
  outP[t] = ga.x * ea.x + ga.y * ea.y + ga.z * ea.z + ga.w * ea.w +
            gb.x * eb.x + gb.y * eb.y + gb.z * eb.z + gb.w * eb.w;
}

// ---------------- launch ----------------

extern "C" void kernel_launch(void* const* d_in, const int* in_sizes, int n_in,
                              void* d_out, int out_size, void* d_ws, size_t ws_size,
                              hipStream_t stream) {
  const float* x  = (const float*)d_in[0];
  const float* W1 = (const float*)d_in[1];
  const float* b1 = (const float*)d_in[2];
  const float* W2 = (const float*)d_in[3];
  const float* b2 = (const float*)d_in[4];
  const float* W3 = (const float*)d_in[5];
  const float* b3 = (const float*)d_in[6];
  const float* Wg = (const float*)d_in[7];
  const float* bg = (const float*)d_in[8];
  float* outP = (float*)d_out;   // predictions [B] f32
  float* outG = outP + NTOK;     // gate [B][8] f32

  char* ws = (char*)d_ws;
  unsigned short* W1t  = (unsigned short*)ws;               //  5,242,880
  unsigned short* W2t  = (unsigned short*)(ws + 5242880ll); //    524,288
  unsigned short* WgTb = (unsigned short*)(ws + 5767168ll); //     40,960
  float*          eo   = (float*)(ws + 5808128ll);          //  2,097,152  (tot ~7.9MB)

  pack_all_kernel<<<1488, 256, 0, stream>>>(W1, W2, Wg, W1t, W2t, WgTb);
  expert_fused_kernel<<<dim3(8, 1024), 256, 0, stream>>>(x, W1t, b1, W2t, b2, W3, b3,
                                                         WgTb, bg, outG, eo);
  combine_kernel<<<256, 256, 0, stream>>>(outG, eo, outP);
}